// Round 1
// baseline (1240.783 us; speedup 1.0000x reference)
//
#include <hip/hip_runtime.h>
#include <math.h>

#define N_ 100000
#define E_ 400000
#define G_ 200
#define D_ 128
#define H_ 4
#define C_ 32
#define L_ 4
#define NEG 0.2f

__device__ __forceinline__ float lrelu(float x){ return x > 0.f ? x : NEG * x; }

// ---------------- node embed: h = relu(x @ W0 + b0) ----------------
__global__ __launch_bounds__(128) void k_embed(const float* __restrict__ x,
    const float* __restrict__ W0, const float* __restrict__ b0, float* __restrict__ h){
  __shared__ float sx[9];
  int i = blockIdx.x, t = threadIdx.x;
  if (t < 9) sx[t] = x[i*9 + t];
  __syncthreads();
  float a = b0[t];
  #pragma unroll
  for (int k = 0; k < 9; ++k) a += sx[k] * W0[k*D_ + t];
  h[(size_t)i*D_ + t] = fmaxf(a, 0.f);
}

// ---------------- GEMM: hW = h @ Wg[l]  (128x128 weight) ----------------
#define GR 32
__global__ __launch_bounds__(256) void k_gemm(const float* __restrict__ A,
    const float* __restrict__ W, float* __restrict__ Cm){
  __shared__ float sA[GR][D_ + 1];
  int r0 = blockIdx.x * GR;
  for (int idx = threadIdx.x; idx < GR*D_; idx += 256){
    sA[idx >> 7][idx & 127] = A[(size_t)(r0 + (idx >> 7))*D_ + (idx & 127)];
  }
  __syncthreads();
  int rg = threadIdx.x >> 5, cg = threadIdx.x & 31;
  float acc[4][4] = {};
  for (int k = 0; k < D_; ++k){
    float4 b = *(const float4*)&W[k*D_ + cg*4];
    #pragma unroll
    for (int r = 0; r < 4; ++r){
      float a = sA[rg*4 + r][k];
      acc[r][0] += a*b.x; acc[r][1] += a*b.y; acc[r][2] += a*b.z; acc[r][3] += a*b.w;
    }
  }
  #pragma unroll
  for (int r = 0; r < 4; ++r){
    float4 v = make_float4(acc[r][0], acc[r][1], acc[r][2], acc[r][3]);
    *(float4*)&Cm[(size_t)(r0 + rg*4 + r)*D_ + cg*4] = v;
  }
}

// ---------------- alpha_src / alpha_dst per (node, head) ----------------
__global__ __launch_bounds__(256) void k_alpha(const float* __restrict__ hW,
    const float* __restrict__ a_s, const float* __restrict__ a_d,
    float* __restrict__ asr, float* __restrict__ adt){
  int idx = blockIdx.x*256 + threadIdx.x;
  if (idx >= N_*H_) return;
  int hh = idx & 3;
  size_t base = (size_t)(idx >> 2)*D_ + hh*C_;
  float s1 = 0.f, s2 = 0.f;
  #pragma unroll
  for (int c = 0; c < C_; c += 4){
    float4 v = *(const float4*)&hW[base + c];
    float4 u = *(const float4*)&a_s[hh*C_ + c];
    float4 w = *(const float4*)&a_d[hh*C_ + c];
    s1 += v.x*u.x + v.y*u.y + v.z*u.z + v.w*u.w;
    s2 += v.x*w.x + v.y*w.y + v.z*w.z + v.w*w.w;
  }
  asr[idx] = s1; adt[idx] = s2;
}

// ---------------- CSR build ----------------
__global__ __launch_bounds__(256) void k_count(const int* __restrict__ dst, int* __restrict__ cnt){
  int e = blockIdx.x*256 + threadIdx.x;
  if (e < E_) atomicAdd(&cnt[dst[e]], 1);
}

__global__ __launch_bounds__(256) void k_scan_sums(const int* __restrict__ cnt, int* __restrict__ bsum, int n){
  __shared__ int sd[256];
  int base = blockIdx.x*1024 + threadIdx.x*4;
  int s = 0;
  #pragma unroll
  for (int j = 0; j < 4; ++j){ int i = base + j; if (i < n) s += cnt[i]; }
  sd[threadIdx.x] = s; __syncthreads();
  for (int o = 128; o; o >>= 1){
    if (threadIdx.x < o) sd[threadIdx.x] += sd[threadIdx.x + o];
    __syncthreads();
  }
  if (threadIdx.x == 0) bsum[blockIdx.x] = sd[0];
}

__global__ void k_scan_top(int* bsum, int nblk, int* off){
  if (threadIdx.x == 0 && blockIdx.x == 0){
    int run = 0;
    for (int b = 0; b < nblk; ++b){ int t = bsum[b]; bsum[b] = run; run += t; }
    off[N_] = run;   // == E_
  }
}

__global__ __launch_bounds__(256) void k_scan_apply(const int* __restrict__ cnt,
    const int* __restrict__ bsum, int* __restrict__ off, int n){
  __shared__ int sT[256];
  int base = blockIdx.x*1024 + threadIdx.x*4;
  int v[4]; int t = 0;
  #pragma unroll
  for (int j = 0; j < 4; ++j){ int i = base + j; v[j] = (i < n) ? cnt[i] : 0; t += v[j]; }
  sT[threadIdx.x] = t; __syncthreads();
  for (int o = 1; o < 256; o <<= 1){
    int xv = (threadIdx.x >= o) ? sT[threadIdx.x - o] : 0;
    __syncthreads();
    sT[threadIdx.x] += xv;
    __syncthreads();
  }
  int excl = sT[threadIdx.x] - t;
  int b0v = bsum[blockIdx.x];
  int pre = 0;
  #pragma unroll
  for (int j = 0; j < 4; ++j){ int i = base + j; if (i < n) off[i] = b0v + excl + pre; pre += v[j]; }
}

__global__ __launch_bounds__(256) void k_fill(const int* __restrict__ src, const int* __restrict__ dst,
    const int* __restrict__ off, int* __restrict__ cnt2, int* __restrict__ csr){
  int e = blockIdx.x*256 + threadIdx.x;
  if (e < E_){
    int d = dst[e];
    int pos = off[d] + atomicAdd(&cnt2[d], 1);
    csr[pos] = src[e];
  }
}

// ---------------- fused GAT aggregate + bias + LN + ReLU + residual ----------------
__global__ __launch_bounds__(128) void k_gat(const float* __restrict__ hW,
    const float* __restrict__ asr, const float* __restrict__ adt,
    const int* __restrict__ off, const int* __restrict__ csr,
    const float* __restrict__ bg, const float* __restrict__ lng, const float* __restrict__ lnb,
    float* __restrict__ h){
  __shared__ float s_ad[4], s_eself[4], s_m[4], s_wself[4], s_invz[4];
  __shared__ float s_red[2][4];
  __shared__ float s_w[128][4];
  __shared__ int   s_src[128];
  __shared__ float s_ln[2];
  int i = blockIdx.x, t = threadIdx.x;
  int beg = off[i], end = off[i + 1];

  if (t < 4){
    float advl = adt[i*4 + t];
    s_ad[t] = advl;
    s_eself[t] = lrelu(asr[i*4 + t] + advl);   // self-loop coefficient
  }
  __syncthreads();
  float ad0 = s_ad[0], ad1 = s_ad[1], ad2 = s_ad[2], ad3 = s_ad[3];

  // phase A: per-head max over incoming edges
  float lm[4] = {-INFINITY, -INFINITY, -INFINITY, -INFINITY};
  for (int k = beg + t; k < end; k += 128){
    int s = csr[k];
    float4 as = *(const float4*)&asr[s*4];
    lm[0] = fmaxf(lm[0], lrelu(as.x + ad0));
    lm[1] = fmaxf(lm[1], lrelu(as.y + ad1));
    lm[2] = fmaxf(lm[2], lrelu(as.z + ad2));
    lm[3] = fmaxf(lm[3], lrelu(as.w + ad3));
  }
  #pragma unroll
  for (int o = 32; o; o >>= 1){
    #pragma unroll
    for (int q = 0; q < 4; ++q) lm[q] = fmaxf(lm[q], __shfl_down(lm[q], o));
  }
  if ((t & 63) == 0){ int w = t >> 6; for (int q = 0; q < 4; ++q) s_red[w][q] = lm[q]; }
  __syncthreads();
  if (t < 4) s_m[t] = fmaxf(fmaxf(s_red[0][t], s_red[1][t]), s_eself[t]);
  __syncthreads();
  float m0 = s_m[0], m1 = s_m[1], m2 = s_m[2], m3 = s_m[3];

  // phase B: per-head softmax denominator
  float lz[4] = {0.f, 0.f, 0.f, 0.f};
  for (int k = beg + t; k < end; k += 128){
    int s = csr[k];
    float4 as = *(const float4*)&asr[s*4];
    lz[0] += __expf(lrelu(as.x + ad0) - m0);
    lz[1] += __expf(lrelu(as.y + ad1) - m1);
    lz[2] += __expf(lrelu(as.z + ad2) - m2);
    lz[3] += __expf(lrelu(as.w + ad3) - m3);
  }
  #pragma unroll
  for (int o = 32; o; o >>= 1){
    #pragma unroll
    for (int q = 0; q < 4; ++q) lz[q] += __shfl_down(lz[q], o);
  }
  if ((t & 63) == 0){ int w = t >> 6; for (int q = 0; q < 4; ++q) s_red[w][q] = lz[q]; }
  __syncthreads();
  if (t < 4){
    float es = __expf(s_eself[t] - s_m[t]);
    float z = s_red[0][t] + s_red[1][t] + es;
    float iz = 1.f / (z + 1e-16f);
    s_invz[t] = iz;
    s_wself[t] = es * iz;
  }
  __syncthreads();

  // phase C: weighted aggregation (self loop + edges, chunked through LDS)
  int hd = t >> 5;
  float acc = s_wself[hd] * hW[(size_t)i*D_ + t];
  for (int cb = beg; cb < end; cb += 128){
    int k = cb + t;
    if (k < end){
      int s = csr[k];
      float4 as = *(const float4*)&asr[s*4];
      s_w[t][0] = __expf(lrelu(as.x + ad0) - m0) * s_invz[0];
      s_w[t][1] = __expf(lrelu(as.y + ad1) - m1) * s_invz[1];
      s_w[t][2] = __expf(lrelu(as.z + ad2) - m2) * s_invz[2];
      s_w[t][3] = __expf(lrelu(as.w + ad3) - m3) * s_invz[3];
      s_src[t] = s;
    }
    __syncthreads();
    int cn = min(128, end - cb);
    for (int j = 0; j < cn; ++j){
      acc += s_w[j][hd] * hW[(size_t)s_src[j]*D_ + t];
    }
    __syncthreads();
  }

  // bias + LayerNorm + ReLU + residual (in place: only this block touches row i)
  float v = acc + bg[t];
  float sm = v;
  #pragma unroll
  for (int o = 32; o; o >>= 1) sm += __shfl_down(sm, o);
  __syncthreads();
  if ((t & 63) == 0) s_ln[t >> 6] = sm;
  __syncthreads();
  float mu = (s_ln[0] + s_ln[1]) * (1.f/128.f);
  float dv = v - mu;
  float sv = dv * dv;
  #pragma unroll
  for (int o = 32; o; o >>= 1) sv += __shfl_down(sv, o);
  __syncthreads();
  if ((t & 63) == 0) s_ln[t >> 6] = sv;
  __syncthreads();
  float var = (s_ln[0] + s_ln[1]) * (1.f/128.f);
  float y = dv * rsqrtf(var + 1e-5f) * lng[t] + lnb[t];
  h[(size_t)i*D_ + t] += fmaxf(y, 0.f);
}

// ---------------- pooling ----------------
__global__ __launch_bounds__(256) void k_starts(const int* __restrict__ batch, int* __restrict__ gst){
  int i = blockIdx.x*256 + threadIdx.x;
  if (i >= N_) return;
  int b = batch[i];
  if (i == 0){
    for (int g = 0; g <= b; ++g) gst[g] = 0;
  } else {
    int pb = batch[i - 1];
    for (int g = pb + 1; g <= b; ++g) gst[g] = i;
  }
  if (i == N_ - 1){
    for (int g = b + 1; g <= G_; ++g) gst[g] = N_;
  }
}

__global__ __launch_bounds__(128) void k_pool(const float* __restrict__ h,
    const int* __restrict__ gst, float* __restrict__ pooled){
  int g = blockIdx.x, d = threadIdx.x;
  int b = gst[g], e = gst[g + 1];
  float acc = 0.f;
  for (int r = b; r < e; ++r) acc += h[(size_t)r*D_ + d];
  pooled[g*D_ + d] = acc / fmaxf((float)(e - b), 1.0f);
}

// ---------------- output head: relu(pooled@W1+b1)@W2+b2 ----------------
__global__ __launch_bounds__(128) void k_out(const float* __restrict__ pooled,
    const float* __restrict__ W1, const float* __restrict__ b1,
    const float* __restrict__ W2, const float* __restrict__ b2, float* __restrict__ out){
  __shared__ float sp[128], st[128];
  int g = blockIdx.x, t = threadIdx.x;
  sp[t] = pooled[g*D_ + t];
  __syncthreads();
  float a = b1[t];
  for (int k = 0; k < D_; ++k) a += sp[k] * W1[k*D_ + t];
  st[t] = fmaxf(a, 0.f);
  __syncthreads();
  float o = b2[t];
  for (int k = 0; k < D_; ++k) o += st[k] * W2[k*D_ + t];
  out[g*D_ + t] = o;
}

extern "C" void kernel_launch(void* const* d_in, const int* in_sizes, int n_in,
                              void* d_out, int out_size, void* d_ws, size_t ws_size,
                              hipStream_t stream){
  const float* x   = (const float*)d_in[0];
  const int*   ei  = (const int*)d_in[1];
  const int*   bat = (const int*)d_in[2];
  const float* W0  = (const float*)d_in[3];
  const float* b0  = (const float*)d_in[4];
  const float* Wg  = (const float*)d_in[5];
  const float* a_s = (const float*)d_in[6];
  const float* a_d = (const float*)d_in[7];
  const float* bg  = (const float*)d_in[8];
  const float* lng = (const float*)d_in[9];
  const float* lnb = (const float*)d_in[10];
  const float* W1  = (const float*)d_in[11];
  const float* b1  = (const float*)d_in[12];
  const float* W2  = (const float*)d_in[13];
  const float* b2  = (const float*)d_in[14];
  const int* src = ei;
  const int* dst = ei + E_;

  char* p = (char*)d_ws;
  auto alloc = [&](size_t b){ void* r = (void*)p; p += (b + 255) & ~(size_t)255; return r; };
  float* h    = (float*)alloc((size_t)N_*D_*4);
  float* hW   = (float*)alloc((size_t)N_*D_*4);
  float* asr  = (float*)alloc((size_t)N_*H_*4);
  float* adt  = (float*)alloc((size_t)N_*H_*4);
  int*   cnt  = (int*)alloc((size_t)N_*4);
  int*   cnt2 = (int*)alloc((size_t)N_*4);
  int*   off  = (int*)alloc((size_t)(N_ + 1)*4);
  int*   bsum = (int*)alloc(1024);
  int*   csr  = (int*)alloc((size_t)E_*4);
  int*   gst  = (int*)alloc((size_t)(G_ + 1)*4);
  float* pooled = (float*)alloc((size_t)G_*D_*4);

  hipMemsetAsync(cnt,  0, (size_t)N_*4, stream);
  hipMemsetAsync(cnt2, 0, (size_t)N_*4, stream);

  k_embed<<<N_, 128, 0, stream>>>(x, W0, b0, h);

  int nblk = (N_ + 1023) / 1024;
  k_count<<<(E_ + 255)/256, 256, 0, stream>>>(dst, cnt);
  k_scan_sums<<<nblk, 256, 0, stream>>>(cnt, bsum, N_);
  k_scan_top<<<1, 64, 0, stream>>>(bsum, nblk, off);
  k_scan_apply<<<nblk, 256, 0, stream>>>(cnt, bsum, off, N_);
  k_fill<<<(E_ + 255)/256, 256, 0, stream>>>(src, dst, off, cnt2, csr);

  for (int l = 0; l < L_; ++l){
    k_gemm<<<N_/GR, 256, 0, stream>>>(h, Wg + (size_t)l*D_*D_, hW);
    k_alpha<<<(N_*H_ + 255)/256, 256, 0, stream>>>(hW, a_s + l*H_*C_, a_d + l*H_*C_, asr, adt);
    k_gat<<<N_, 128, 0, stream>>>(hW, asr, adt, off, csr, bg + l*D_, lng + l*D_, lnb + l*D_, h);
  }

  k_starts<<<(N_ + 255)/256, 256, 0, stream>>>(bat, gst);
  k_pool<<<G_, 128, 0, stream>>>(h, gst, pooled);
  k_out<<<G_, 128, 0, stream>>>(pooled, W1, b1, W2, b2, (float*)d_out);
}

// Round 29
// 796.139 us; speedup vs baseline: 1.5585x; 1.5585x over previous
//
#include <hip/hip_runtime.h>
#include <math.h>

#define N_ 100000
#define E_ 400000
#define G_ 200
#define D_ 128
#define H_ 4
#define C_ 32
#define L_ 4
#define NEG 0.2f

__device__ __forceinline__ float lrelu(float x){ return x > 0.f ? x : NEG * x; }

// ---------------- node embed: h = relu(x @ W0 + b0) ----------------
__global__ __launch_bounds__(128) void k_embed(const float* __restrict__ x,
    const float* __restrict__ W0, const float* __restrict__ b0, float* __restrict__ h){
  __shared__ float sx[9];
  int i = blockIdx.x, t = threadIdx.x;
  if (t < 9) sx[t] = x[i*9 + t];
  __syncthreads();
  float a = b0[t];
  #pragma unroll
  for (int k = 0; k < 9; ++k) a += sx[k] * W0[k*D_ + t];
  h[(size_t)i*D_ + t] = fmaxf(a, 0.f);
}

// ---------------- GEMM: hW = h @ Wg[l]  (128x128 weight) ----------------
#define GR 32
__global__ __launch_bounds__(256) void k_gemm(const float* __restrict__ A,
    const float* __restrict__ W, float* __restrict__ Cm){
  __shared__ float sA[GR][D_ + 1];
  int r0 = blockIdx.x * GR;
  for (int idx = threadIdx.x; idx < GR*D_; idx += 256){
    sA[idx >> 7][idx & 127] = A[(size_t)(r0 + (idx >> 7))*D_ + (idx & 127)];
  }
  __syncthreads();
  int rg = threadIdx.x >> 5, cg = threadIdx.x & 31;
  float acc[4][4] = {};
  for (int k = 0; k < D_; ++k){
    float4 b = *(const float4*)&W[k*D_ + cg*4];
    #pragma unroll
    for (int r = 0; r < 4; ++r){
      float a = sA[rg*4 + r][k];
      acc[r][0] += a*b.x; acc[r][1] += a*b.y; acc[r][2] += a*b.z; acc[r][3] += a*b.w;
    }
  }
  #pragma unroll
  for (int r = 0; r < 4; ++r){
    float4 v = make_float4(acc[r][0], acc[r][1], acc[r][2], acc[r][3]);
    *(float4*)&Cm[(size_t)(r0 + rg*4 + r)*D_ + cg*4] = v;
  }
}

// ---------------- alpha_src / alpha_dst per (node, head) ----------------
__global__ __launch_bounds__(256) void k_alpha(const float* __restrict__ hW,
    const float* __restrict__ a_s, const float* __restrict__ a_d,
    float* __restrict__ asr, float* __restrict__ adt){
  int idx = blockIdx.x*256 + threadIdx.x;
  if (idx >= N_*H_) return;
  int hh = idx & 3;
  size_t base = (size_t)(idx >> 2)*D_ + hh*C_;
  float s1 = 0.f, s2 = 0.f;
  #pragma unroll
  for (int c = 0; c < C_; c += 4){
    float4 v = *(const float4*)&hW[base + c];
    float4 u = *(const float4*)&a_s[hh*C_ + c];
    float4 w = *(const float4*)&a_d[hh*C_ + c];
    s1 += v.x*u.x + v.y*u.y + v.z*u.z + v.w*u.w;
    s2 += v.x*w.x + v.y*w.y + v.z*w.z + v.w*w.w;
  }
  asr[idx] = s1; adt[idx] = s2;
}

// ---------------- CSR build ----------------
__global__ __launch_bounds__(256) void k_count(const int* __restrict__ dst, int* __restrict__ cnt){
  int e = blockIdx.x*256 + threadIdx.x;
  if (e < E_) atomicAdd(&cnt[dst[e]], 1);
}

__global__ __launch_bounds__(256) void k_scan_sums(const int* __restrict__ cnt, int* __restrict__ bsum, int n){
  __shared__ int sd[256];
  int base = blockIdx.x*1024 + threadIdx.x*4;
  int s = 0;
  #pragma unroll
  for (int j = 0; j < 4; ++j){ int i = base + j; if (i < n) s += cnt[i]; }
  sd[threadIdx.x] = s; __syncthreads();
  for (int o = 128; o; o >>= 1){
    if (threadIdx.x < o) sd[threadIdx.x] += sd[threadIdx.x + o];
    __syncthreads();
  }
  if (threadIdx.x == 0) bsum[blockIdx.x] = sd[0];
}

__global__ void k_scan_top(int* bsum, int nblk, int* off){
  if (threadIdx.x == 0 && blockIdx.x == 0){
    int run = 0;
    for (int b = 0; b < nblk; ++b){ int t = bsum[b]; bsum[b] = run; run += t; }
    off[N_] = run;   // == E_
  }
}

__global__ __launch_bounds__(256) void k_scan_apply(const int* __restrict__ cnt,
    const int* __restrict__ bsum, int* __restrict__ off, int n){
  __shared__ int sT[256];
  int base = blockIdx.x*1024 + threadIdx.x*4;
  int v[4]; int t = 0;
  #pragma unroll
  for (int j = 0; j < 4; ++j){ int i = base + j; v[j] = (i < n) ? cnt[i] : 0; t += v[j]; }
  sT[threadIdx.x] = t; __syncthreads();
  for (int o = 1; o < 256; o <<= 1){
    int xv = (threadIdx.x >= o) ? sT[threadIdx.x - o] : 0;
    __syncthreads();
    sT[threadIdx.x] += xv;
    __syncthreads();
  }
  int excl = sT[threadIdx.x] - t;
  int b0v = bsum[blockIdx.x];
  int pre = 0;
  #pragma unroll
  for (int j = 0; j < 4; ++j){ int i = base + j; if (i < n) off[i] = b0v + excl + pre; pre += v[j]; }
}

__global__ __launch_bounds__(256) void k_fill(const int* __restrict__ src, const int* __restrict__ dst,
    const int* __restrict__ off, int* __restrict__ cnt2, int* __restrict__ csr){
  int e = blockIdx.x*256 + threadIdx.x;
  if (e < E_){
    int d = dst[e];
    int pos = off[d] + atomicAdd(&cnt2[d], 1);
    csr[pos] = src[e];
  }
}

// ---------------- fused GAT: one WAVE per node ----------------
// lane layout, weight phase: edge-group e = l>>2 (16 edges/chunk), head hh = l&3
// lane layout, aggregation:  channels c0 = l, c1 = l + 64
__global__ __launch_bounds__(256) void k_gat(const float* __restrict__ hW,
    const float* __restrict__ asr, const float* __restrict__ adt,
    const int* __restrict__ off, const int* __restrict__ csr,
    const float* __restrict__ bg, const float* __restrict__ lng, const float* __restrict__ lnb,
    float* __restrict__ h){
  int i = (blockIdx.x * 256 + threadIdx.x) >> 6;   // node = global wave id
  int l = threadIdx.x & 63;
  int beg = off[i], end = off[i + 1];
  int hh = l & 3;

  float adv = adt[i*4 + hh];
  float sself = lrelu(asr[i*4 + hh] + adv);

  // ---- pass 1: per-head max over edges (+self) ----
  float m = sself;
  for (int cb = beg; cb < end; cb += 16){
    int e = cb + (l >> 2);
    if (e < end){
      int s = csr[e];
      m = fmaxf(m, lrelu(asr[s*4 + hh] + adv));
    }
  }
  m = fmaxf(m, __shfl_xor(m, 4));
  m = fmaxf(m, __shfl_xor(m, 8));
  m = fmaxf(m, __shfl_xor(m, 16));
  m = fmaxf(m, __shfl_xor(m, 32));

  // ---- pass 2: per-head softmax denominator ----
  float z = 0.f;
  for (int cb = beg; cb < end; cb += 16){
    int e = cb + (l >> 2);
    if (e < end){
      int s = csr[e];
      z += __expf(lrelu(asr[s*4 + hh] + adv) - m);
    }
  }
  z += __shfl_xor(z, 4);
  z += __shfl_xor(z, 8);
  z += __shfl_xor(z, 16);
  z += __shfl_xor(z, 32);
  z += __expf(sself - m);              // self contribution (same in all lanes of a head)
  float invz = 1.f / (z + 1e-16f);
  float wsl = __expf(sself - m) * invz;

  // heads owned by my two channels
  int h0 = l >> 5, h1 = 2 + h0;
  float ws0 = __shfl(wsl, h0), ws1 = __shfl(wsl, h1);

  // ---- pass 3: weighted aggregation ----
  size_t ibase = (size_t)i * D_;
  float acc0 = ws0 * hW[ibase + l];
  float acc1 = ws1 * hW[ibase + 64 + l];
  for (int cb = beg; cb < end; cb += 16){
    int e = cb + (l >> 2);
    float al = 0.f; int s = 0;
    if (e < end){
      s = csr[e];
      al = __expf(lrelu(asr[s*4 + hh] + adv) - m) * invz;
    }
    int cn = min(16, end - cb);
    for (int j = 0; j < cn; ++j){
      int   sj = __shfl(s,  j*4);
      float a0 = __shfl(al, j*4 + h0);
      float a1 = __shfl(al, j*4 + h1);
      size_t b = (size_t)sj * D_;
      acc0 += a0 * hW[b + l];
      acc1 += a1 * hW[b + 64 + l];
    }
  }

  // ---- bias + LayerNorm + ReLU + residual ----
  float v0 = acc0 + bg[l], v1 = acc1 + bg[l + 64];
  float sm = v0 + v1;
  #pragma unroll
  for (int o = 1; o < 64; o <<= 1) sm += __shfl_xor(sm, o);
  float mu = sm * (1.f/128.f);
  float d0 = v0 - mu, d1 = v1 - mu;
  float sv = d0*d0 + d1*d1;
  #pragma unroll
  for (int o = 1; o < 64; o <<= 1) sv += __shfl_xor(sv, o);
  float r = rsqrtf(sv * (1.f/128.f) + 1e-5f);
  float y0 = d0 * r * lng[l]      + lnb[l];
  float y1 = d1 * r * lng[l + 64] + lnb[l + 64];
  h[ibase + l]      += fmaxf(y0, 0.f);
  h[ibase + 64 + l] += fmaxf(y1, 0.f);
}

// ---------------- pooling ----------------
__global__ __launch_bounds__(256) void k_starts(const int* __restrict__ batch, int* __restrict__ gst){
  int i = blockIdx.x*256 + threadIdx.x;
  if (i >= N_) return;
  int b = batch[i];
  if (i == 0){
    for (int g = 0; g <= b; ++g) gst[g] = 0;
  } else {
    int pb = batch[i - 1];
    for (int g = pb + 1; g <= b; ++g) gst[g] = i;
  }
  if (i == N_ - 1){
    for (int g = b + 1; g <= G_; ++g) gst[g] = N_;
  }
}

// chunked: 128 rows per block, flush partial sums at graph boundaries
__global__ __launch_bounds__(128) void k_pool(const float* __restrict__ h,
    const int* __restrict__ batch, float* __restrict__ pooled){
  int t = threadIdx.x;
  int r0 = blockIdx.x * 128;
  int rend = min(r0 + 128, N_);
  float acc = 0.f;
  int pg = batch[r0];
  for (int r = r0; r < rend; ++r){
    int g = batch[r];
    if (g != pg){ atomicAdd(&pooled[pg*D_ + t], acc); acc = 0.f; pg = g; }
    acc += h[(size_t)r*D_ + t];
  }
  atomicAdd(&pooled[pg*D_ + t], acc);
}

// ---------------- output head: relu(mean@W1+b1)@W2+b2 ----------------
__global__ __launch_bounds__(128) void k_out(const float* __restrict__ pooled,
    const int* __restrict__ gst,
    const float* __restrict__ W1, const float* __restrict__ b1,
    const float* __restrict__ W2, const float* __restrict__ b2, float* __restrict__ out){
  __shared__ float sp[128], st[128];
  int g = blockIdx.x, t = threadIdx.x;
  float cntg = (float)(gst[g + 1] - gst[g]);
  sp[t] = pooled[g*D_ + t] / fmaxf(cntg, 1.0f);
  __syncthreads();
  float a = b1[t];
  for (int k = 0; k < D_; ++k) a += sp[k] * W1[k*D_ + t];
  st[t] = fmaxf(a, 0.f);
  __syncthreads();
  float o = b2[t];
  for (int k = 0; k < D_; ++k) o += st[k] * W2[k*D_ + t];
  out[g*D_ + t] = o;
}

extern "C" void kernel_launch(void* const* d_in, const int* in_sizes, int n_in,
                              void* d_out, int out_size, void* d_ws, size_t ws_size,
                              hipStream_t stream){
  const float* x   = (const float*)d_in[0];
  const int*   ei  = (const int*)d_in[1];
  const int*   bat = (const int*)d_in[2];
  const float* W0  = (const float*)d_in[3];
  const float* b0  = (const float*)d_in[4];
  const float* Wg  = (const float*)d_in[5];
  const float* a_s = (const float*)d_in[6];
  const float* a_d = (const float*)d_in[7];
  const float* bg  = (const float*)d_in[8];
  const float* lng = (const float*)d_in[9];
  const float* lnb = (const float*)d_in[10];
  const float* W1  = (const float*)d_in[11];
  const float* b1  = (const float*)d_in[12];
  const float* W2  = (const float*)d_in[13];
  const float* b2  = (const float*)d_in[14];
  const int* src = ei;
  const int* dst = ei + E_;

  char* p = (char*)d_ws;
  auto alloc = [&](size_t b){ void* r = (void*)p; p += (b + 255) & ~(size_t)255; return r; };
  float* h    = (float*)alloc((size_t)N_*D_*4);
  float* hW   = (float*)alloc((size_t)N_*D_*4);
  float* asr  = (float*)alloc((size_t)N_*H_*4);
  float* adt  = (float*)alloc((size_t)N_*H_*4);
  int*   cnt  = (int*)alloc((size_t)N_*4);
  int*   cnt2 = (int*)alloc((size_t)N_*4);
  int*   off  = (int*)alloc((size_t)(N_ + 1)*4);
  int*   bsum = (int*)alloc(1024);
  int*   csr  = (int*)alloc((size_t)E_*4);
  int*   gst  = (int*)alloc((size_t)(G_ + 1)*4);
  float* pooled = (float*)alloc((size_t)G_*D_*4);

  hipError_t err;
  err = hipMemsetAsync(cnt,  0, (size_t)N_*4, stream); (void)err;
  err = hipMemsetAsync(cnt2, 0, (size_t)N_*4, stream); (void)err;
  err = hipMemsetAsync(pooled, 0, (size_t)G_*D_*4, stream); (void)err;

  k_embed<<<N_, 128, 0, stream>>>(x, W0, b0, h);

  int nblk = (N_ + 1023) / 1024;
  k_count<<<(E_ + 255)/256, 256, 0, stream>>>(dst, cnt);
  k_scan_sums<<<nblk, 256, 0, stream>>>(cnt, bsum, N_);
  k_scan_top<<<1, 64, 0, stream>>>(bsum, nblk, off);
  k_scan_apply<<<nblk, 256, 0, stream>>>(cnt, bsum, off, N_);
  k_fill<<<(E_ + 255)/256, 256, 0, stream>>>(src, dst, off, cnt2, csr);

  for (int l = 0; l < L_; ++l){
    k_gemm<<<N_/GR, 256, 0, stream>>>(h, Wg + (size_t)l*D_*D_, hW);
    k_alpha<<<(N_*H_ + 255)/256, 256, 0, stream>>>(hW, a_s + l*H_*C_, a_d + l*H_*C_, asr, adt);
    k_gat<<<N_/4, 256, 0, stream>>>(hW, asr, adt, off, csr, bg + l*D_, lng + l*D_, lnb + l*D_, h);
  }

  k_starts<<<(N_ + 255)/256, 256, 0, stream>>>(bat, gst);
  k_pool<<<(N_ + 127)/128, 128, 0, stream>>>(h, bat, pooled);
  k_out<<<G_, 128, 0, stream>>>(pooled, gst, W1, b1, W2, b2, (float*)d_out);
}

// Round 32
// 697.337 us; speedup vs baseline: 1.7793x; 1.1417x over previous
//
#include <hip/hip_runtime.h>
#include <math.h>

#define N_ 100000
#define E_ 400000
#define G_ 200
#define D_ 128
#define H_ 4
#define C_ 32
#define L_ 4
#define NEG 0.2f

__device__ __forceinline__ float lrelu(float x){ return x > 0.f ? x : NEG * x; }

// ---------------- node embed: h = relu(x @ W0 + b0) ----------------
__global__ __launch_bounds__(128) void k_embed(const float* __restrict__ x,
    const float* __restrict__ W0, const float* __restrict__ b0, float* __restrict__ h){
  __shared__ float sx[9];
  int i = blockIdx.x, t = threadIdx.x;
  if (t < 9) sx[t] = x[i*9 + t];
  __syncthreads();
  float a = b0[t];
  #pragma unroll
  for (int k = 0; k < 9; ++k) a += sx[k] * W0[k*D_ + t];
  h[(size_t)i*D_ + t] = fmaxf(a, 0.f);
}

// ---- GEMM: hW = h @ Wg[l], fused alpha epilogue (asr/adt per node,head) ----
#define GR 32
__global__ __launch_bounds__(256) void k_gemm(const float* __restrict__ A,
    const float* __restrict__ W,
    const float* __restrict__ a_s, const float* __restrict__ a_d,
    float* __restrict__ Cm, float* __restrict__ asr, float* __restrict__ adt){
  __shared__ float sA[GR][D_ + 1];
  int r0 = blockIdx.x * GR;
  for (int idx = threadIdx.x; idx < GR*D_; idx += 256){
    sA[idx >> 7][idx & 127] = A[(size_t)(r0 + (idx >> 7))*D_ + (idx & 127)];
  }
  __syncthreads();
  int rg = threadIdx.x >> 5, cg = threadIdx.x & 31;
  float acc[4][4] = {};
  for (int k = 0; k < D_; ++k){
    float4 b = *(const float4*)&W[k*D_ + cg*4];
    #pragma unroll
    for (int r = 0; r < 4; ++r){
      float a = sA[rg*4 + r][k];
      acc[r][0] += a*b.x; acc[r][1] += a*b.y; acc[r][2] += a*b.z; acc[r][3] += a*b.w;
    }
  }
  #pragma unroll
  for (int r = 0; r < 4; ++r){
    float4 v = make_float4(acc[r][0], acc[r][1], acc[r][2], acc[r][3]);
    *(float4*)&Cm[(size_t)(r0 + rg*4 + r)*D_ + cg*4] = v;
  }
  // alpha epilogue: my 4 cols lie in head hd, cols-within-head cw..cw+3
  int hd = cg >> 3;
  int cw = (cg & 7) * 4;
  float4 u = *(const float4*)&a_s[hd*C_ + cw];
  float4 w = *(const float4*)&a_d[hd*C_ + cw];
  #pragma unroll
  for (int r = 0; r < 4; ++r){
    float s1 = acc[r][0]*u.x + acc[r][1]*u.y + acc[r][2]*u.z + acc[r][3]*u.w;
    float s2 = acc[r][0]*w.x + acc[r][1]*w.y + acc[r][2]*w.z + acc[r][3]*w.w;
    s1 += __shfl_xor(s1, 1); s1 += __shfl_xor(s1, 2); s1 += __shfl_xor(s1, 4);
    s2 += __shfl_xor(s2, 1); s2 += __shfl_xor(s2, 2); s2 += __shfl_xor(s2, 4);
    if ((cg & 7) == 0){
      int row = r0 + rg*4 + r;
      asr[row*4 + hd] = s1;
      adt[row*4 + hd] = s2;
    }
  }
}

// ---------------- CSR build ----------------
__global__ __launch_bounds__(256) void k_count(const int* __restrict__ dst, int* __restrict__ cnt){
  int e = blockIdx.x*256 + threadIdx.x;
  if (e < E_) atomicAdd(&cnt[dst[e]], 1);
}

__global__ __launch_bounds__(256) void k_scan_sums(const int* __restrict__ cnt, int* __restrict__ bsum, int n){
  __shared__ int sd[256];
  int base = blockIdx.x*1024 + threadIdx.x*4;
  int s = 0;
  #pragma unroll
  for (int j = 0; j < 4; ++j){ int i = base + j; if (i < n) s += cnt[i]; }
  sd[threadIdx.x] = s; __syncthreads();
  for (int o = 128; o; o >>= 1){
    if (threadIdx.x < o) sd[threadIdx.x] += sd[threadIdx.x + o];
    __syncthreads();
  }
  if (threadIdx.x == 0) bsum[blockIdx.x] = sd[0];
}

__global__ void k_scan_top(int* bsum, int nblk, int* off){
  if (threadIdx.x == 0 && blockIdx.x == 0){
    int run = 0;
    for (int b = 0; b < nblk; ++b){ int t = bsum[b]; bsum[b] = run; run += t; }
    off[N_] = run;   // == E_
  }
}

__global__ __launch_bounds__(256) void k_scan_apply(const int* __restrict__ cnt,
    const int* __restrict__ bsum, int* __restrict__ off, int n){
  __shared__ int sT[256];
  int base = blockIdx.x*1024 + threadIdx.x*4;
  int v[4]; int t = 0;
  #pragma unroll
  for (int j = 0; j < 4; ++j){ int i = base + j; v[j] = (i < n) ? cnt[i] : 0; t += v[j]; }
  sT[threadIdx.x] = t; __syncthreads();
  for (int o = 1; o < 256; o <<= 1){
    int xv = (threadIdx.x >= o) ? sT[threadIdx.x - o] : 0;
    __syncthreads();
    sT[threadIdx.x] += xv;
    __syncthreads();
  }
  int excl = sT[threadIdx.x] - t;
  int b0v = bsum[blockIdx.x];
  int pre = 0;
  #pragma unroll
  for (int j = 0; j < 4; ++j){ int i = base + j; if (i < n) off[i] = b0v + excl + pre; pre += v[j]; }
}

__global__ __launch_bounds__(256) void k_fill(const int* __restrict__ src, const int* __restrict__ dst,
    const int* __restrict__ off, int* __restrict__ cnt2, int* __restrict__ csr){
  int e = blockIdx.x*256 + threadIdx.x;
  if (e < E_){
    int d = dst[e];
    int pos = off[d] + atomicAdd(&cnt2[d], 1);
    csr[pos] = src[e];
  }
}

// ---------------- fused GAT: one WAVE per node, online softmax ----------------
// pass 1: online (max, rebased-sum) per head; pass 2: weighted aggregation
__global__ __launch_bounds__(256) void k_gat(const float* __restrict__ hW,
    const float* __restrict__ asr, const float* __restrict__ adt,
    const int* __restrict__ off, const int* __restrict__ csr,
    const float* __restrict__ bg, const float* __restrict__ lng, const float* __restrict__ lnb,
    float* __restrict__ h){
  int i = (blockIdx.x * 256 + threadIdx.x) >> 6;   // node = global wave id
  int l = threadIdx.x & 63;
  int beg = off[i], end = off[i + 1];
  int hh = l & 3;

  float adv = adt[i*4 + hh];
  float sself = lrelu(asr[i*4 + hh] + adv);

  // ---- pass 1: online softmax stats (m = running max, z = rebased sum) ----
  float m = sself;
  float z = ((l >> 2) == 0) ? 1.f : 0.f;   // self term carried by one lane per head
  for (int cb = beg; cb < end; cb += 16){
    int e = cb + (l >> 2);
    if (e < end){
      int s = csr[e];
      float v = lrelu(asr[s*4 + hh] + adv);
      if (v > m){ z *= __expf(m - v); m = v; }
      z += __expf(v - m);
    }
  }
  #pragma unroll
  for (int o = 4; o <= 32; o <<= 1){
    float mo = __shfl_xor(m, o);
    float zo = __shfl_xor(z, o);
    float M = fmaxf(m, mo);
    z = z * __expf(m - M) + zo * __expf(mo - M);
    m = M;
  }
  float invz = 1.f / (z + 1e-16f);
  float wsl = __expf(sself - m) * invz;

  // heads owned by my two channels
  int h0 = l >> 5, h1 = 2 + h0;
  float ws0 = __shfl(wsl, h0), ws1 = __shfl(wsl, h1);

  // ---- pass 2: weighted aggregation ----
  size_t ibase = (size_t)i * D_;
  float acc0 = ws0 * hW[ibase + l];
  float acc1 = ws1 * hW[ibase + 64 + l];
  for (int cb = beg; cb < end; cb += 16){
    int e = cb + (l >> 2);
    float al = 0.f; int s = 0;
    if (e < end){
      s = csr[e];
      al = __expf(lrelu(asr[s*4 + hh] + adv) - m) * invz;
    }
    int cn = min(16, end - cb);
    for (int j = 0; j < cn; ++j){
      int   sj = __shfl(s,  j*4);
      float a0 = __shfl(al, j*4 + h0);
      float a1 = __shfl(al, j*4 + h1);
      size_t b = (size_t)sj * D_;
      acc0 += a0 * hW[b + l];
      acc1 += a1 * hW[b + 64 + l];
    }
  }

  // ---- bias + LayerNorm + ReLU + residual ----
  float v0 = acc0 + bg[l], v1 = acc1 + bg[l + 64];
  float sm = v0 + v1;
  #pragma unroll
  for (int o = 1; o < 64; o <<= 1) sm += __shfl_xor(sm, o);
  float mu = sm * (1.f/128.f);
  float d0 = v0 - mu, d1 = v1 - mu;
  float sv = d0*d0 + d1*d1;
  #pragma unroll
  for (int o = 1; o < 64; o <<= 1) sv += __shfl_xor(sv, o);
  float r = rsqrtf(sv * (1.f/128.f) + 1e-5f);
  float y0 = d0 * r * lng[l]      + lnb[l];
  float y1 = d1 * r * lng[l + 64] + lnb[l + 64];
  h[ibase + l]      += fmaxf(y0, 0.f);
  h[ibase + 64 + l] += fmaxf(y1, 0.f);
}

// ---------------- pooling ----------------
__global__ __launch_bounds__(256) void k_starts(const int* __restrict__ batch, int* __restrict__ gst){
  int i = blockIdx.x*256 + threadIdx.x;
  if (i >= N_) return;
  int b = batch[i];
  if (i == 0){
    for (int g = 0; g <= b; ++g) gst[g] = 0;
  } else {
    int pb = batch[i - 1];
    for (int g = pb + 1; g <= b; ++g) gst[g] = i;
  }
  if (i == N_ - 1){
    for (int g = b + 1; g <= G_; ++g) gst[g] = N_;
  }
}

// chunked: 128 rows per block, flush partial sums at graph boundaries
__global__ __launch_bounds__(128) void k_pool(const float* __restrict__ h,
    const int* __restrict__ batch, float* __restrict__ pooled){
  int t = threadIdx.x;
  int r0 = blockIdx.x * 128;
  int rend = min(r0 + 128, N_);
  float acc = 0.f;
  int pg = batch[r0];
  for (int r = r0; r < rend; ++r){
    int g = batch[r];
    if (g != pg){ atomicAdd(&pooled[pg*D_ + t], acc); acc = 0.f; pg = g; }
    acc += h[(size_t)r*D_ + t];
  }
  atomicAdd(&pooled[pg*D_ + t], acc);
}

// ---------------- output head: relu(mean@W1+b1)@W2+b2 ----------------
__global__ __launch_bounds__(128) void k_out(const float* __restrict__ pooled,
    const int* __restrict__ gst,
    const float* __restrict__ W1, const float* __restrict__ b1,
    const float* __restrict__ W2, const float* __restrict__ b2, float* __restrict__ out){
  __shared__ float sp[128], st[128];
  int g = blockIdx.x, t = threadIdx.x;
  float cntg = (float)(gst[g + 1] - gst[g]);
  sp[t] = pooled[g*D_ + t] / fmaxf(cntg, 1.0f);
  __syncthreads();
  float a = b1[t];
  for (int k = 0; k < D_; ++k) a += sp[k] * W1[k*D_ + t];
  st[t] = fmaxf(a, 0.f);
  __syncthreads();
  float o = b2[t];
  for (int k = 0; k < D_; ++k) o += st[k] * W2[k*D_ + t];
  out[g*D_ + t] = o;
}

extern "C" void kernel_launch(void* const* d_in, const int* in_sizes, int n_in,
                              void* d_out, int out_size, void* d_ws, size_t ws_size,
                              hipStream_t stream){
  const float* x   = (const float*)d_in[0];
  const int*   ei  = (const int*)d_in[1];
  const int*   bat = (const int*)d_in[2];
  const float* W0  = (const float*)d_in[3];
  const float* b0  = (const float*)d_in[4];
  const float* Wg  = (const float*)d_in[5];
  const float* a_s = (const float*)d_in[6];
  const float* a_d = (const float*)d_in[7];
  const float* bg  = (const float*)d_in[8];
  const float* lng = (const float*)d_in[9];
  const float* lnb = (const float*)d_in[10];
  const float* W1  = (const float*)d_in[11];
  const float* b1  = (const float*)d_in[12];
  const float* W2  = (const float*)d_in[13];
  const float* b2  = (const float*)d_in[14];
  const int* src = ei;
  const int* dst = ei + E_;

  char* p = (char*)d_ws;
  auto alloc = [&](size_t b){ void* r = (void*)p; p += (b + 255) & ~(size_t)255; return r; };
  float* h    = (float*)alloc((size_t)N_*D_*4);
  float* hW   = (float*)alloc((size_t)N_*D_*4);
  float* asr  = (float*)alloc((size_t)N_*H_*4);
  float* adt  = (float*)alloc((size_t)N_*H_*4);
  int*   cnt  = (int*)alloc((size_t)N_*4);
  int*   cnt2 = (int*)alloc((size_t)N_*4);
  int*   off  = (int*)alloc((size_t)(N_ + 1)*4);
  int*   bsum = (int*)alloc(1024);
  int*   csr  = (int*)alloc((size_t)E_*4);
  int*   gst  = (int*)alloc((size_t)(G_ + 1)*4);
  float* pooled = (float*)alloc((size_t)G_*D_*4);

  hipError_t err;
  err = hipMemsetAsync(cnt,  0, (size_t)N_*4, stream); (void)err;
  err = hipMemsetAsync(cnt2, 0, (size_t)N_*4, stream); (void)err;
  err = hipMemsetAsync(pooled, 0, (size_t)G_*D_*4, stream); (void)err;

  k_embed<<<N_, 128, 0, stream>>>(x, W0, b0, h);

  int nblk = (N_ + 1023) / 1024;
  k_count<<<(E_ + 255)/256, 256, 0, stream>>>(dst, cnt);
  k_scan_sums<<<nblk, 256, 0, stream>>>(cnt, bsum, N_);
  k_scan_top<<<1, 64, 0, stream>>>(bsum, nblk, off);
  k_scan_apply<<<nblk, 256, 0, stream>>>(cnt, bsum, off, N_);
  k_fill<<<(E_ + 255)/256, 256, 0, stream>>>(src, dst, off, cnt2, csr);

  for (int l = 0; l < L_; ++l){
    k_gemm<<<N_/GR, 256, 0, stream>>>(h, Wg + (size_t)l*D_*D_,
                                      a_s + l*H_*C_, a_d + l*H_*C_, hW, asr, adt);
    k_gat<<<N_/4, 256, 0, stream>>>(hW, asr, adt, off, csr, bg + l*D_, lng + l*D_, lnb + l*D_, h);
  }

  k_starts<<<(N_ + 255)/256, 256, 0, stream>>>(bat, gst);
  k_pool<<<(N_ + 127)/128, 128, 0, stream>>>(h, bat, pooled);
  k_out<<<G_, 128, 0, stream>>>(pooled, gst, W1, b1, W2, b2, (float*)d_out);
}

// Round 37
// 639.881 us; speedup vs baseline: 1.9391x; 1.0898x over previous
//
#include <hip/hip_runtime.h>
#include <math.h>

#define N_ 100000
#define E_ 400000
#define G_ 200
#define D_ 128
#define H_ 4
#define C_ 32
#define L_ 4
#define NEG 0.2f

__device__ __forceinline__ float lrelu(float x){ return x > 0.f ? x : NEG * x; }

// ---------------- node embed: h = relu(x @ W0 + b0) ----------------
__global__ __launch_bounds__(128) void k_embed(const float* __restrict__ x,
    const float* __restrict__ W0, const float* __restrict__ b0, float* __restrict__ h){
  __shared__ float sx[9];
  int i = blockIdx.x, t = threadIdx.x;
  if (t < 9) sx[t] = x[i*9 + t];
  __syncthreads();
  float a = b0[t];
  #pragma unroll
  for (int k = 0; k < 9; ++k) a += sx[k] * W0[k*D_ + t];
  h[(size_t)i*D_ + t] = fmaxf(a, 0.f);
}

// ---- GEMM: hW = h @ Wg[l], LDS-staged W, fused alpha epilogue ----
#define GR 32
__global__ __launch_bounds__(256) void k_gemm(const float* __restrict__ A,
    const float* __restrict__ W,
    const float* __restrict__ a_s, const float* __restrict__ a_d,
    float* __restrict__ Cm, float* __restrict__ asr, float* __restrict__ adt){
  __shared__ float  sA[GR][132];     // padded, 16B-aligned rows (132*4=528=33*16)
  __shared__ float4 sW4[32][32];     // one 32-k chunk of W
  int r0 = blockIdx.x * GR;
  const float4* A4 = (const float4*)A;
  const float4* W4 = (const float4*)W;
  // stage A tile (float4 global reads, scalar LDS writes into padded rows)
  #pragma unroll
  for (int t = 0; t < 4; ++t){
    int idx  = threadIdx.x + t*256;       // 1024 float4s = 32 rows x 32
    int row  = idx >> 5, c4 = idx & 31;
    float4 v = A4[(size_t)(r0 + row)*32 + c4];
    sA[row][c4*4 + 0] = v.x; sA[row][c4*4 + 1] = v.y;
    sA[row][c4*4 + 2] = v.z; sA[row][c4*4 + 3] = v.w;
  }
  int rg = threadIdx.x >> 5, cg = threadIdx.x & 31;
  float acc[4][4] = {};
  for (int k0 = 0; k0 < D_; k0 += 32){
    __syncthreads();                     // protects sW reuse (and sA writes on iter 0)
    #pragma unroll
    for (int t = 0; t < 4; ++t){
      int idx = threadIdx.x + t*256;     // 1024 float4s = 32 k-rows x 32
      sW4[idx >> 5][idx & 31] = W4[(size_t)(k0 + (idx >> 5))*32 + (idx & 31)];
    }
    __syncthreads();
    #pragma unroll
    for (int kk = 0; kk < 32; kk += 4){
      float4 av0 = *(const float4*)&sA[rg*4 + 0][k0 + kk];
      float4 av1 = *(const float4*)&sA[rg*4 + 1][k0 + kk];
      float4 av2 = *(const float4*)&sA[rg*4 + 2][k0 + kk];
      float4 av3 = *(const float4*)&sA[rg*4 + 3][k0 + kk];
      float a0[4] = {av0.x, av0.y, av0.z, av0.w};
      float a1[4] = {av1.x, av1.y, av1.z, av1.w};
      float a2[4] = {av2.x, av2.y, av2.z, av2.w};
      float a3[4] = {av3.x, av3.y, av3.z, av3.w};
      #pragma unroll
      for (int j = 0; j < 4; ++j){
        float4 b = sW4[kk + j][cg];
        acc[0][0] += a0[j]*b.x; acc[0][1] += a0[j]*b.y; acc[0][2] += a0[j]*b.z; acc[0][3] += a0[j]*b.w;
        acc[1][0] += a1[j]*b.x; acc[1][1] += a1[j]*b.y; acc[1][2] += a1[j]*b.z; acc[1][3] += a1[j]*b.w;
        acc[2][0] += a2[j]*b.x; acc[2][1] += a2[j]*b.y; acc[2][2] += a2[j]*b.z; acc[2][3] += a2[j]*b.w;
        acc[3][0] += a3[j]*b.x; acc[3][1] += a3[j]*b.y; acc[3][2] += a3[j]*b.z; acc[3][3] += a3[j]*b.w;
      }
    }
  }
  #pragma unroll
  for (int r = 0; r < 4; ++r){
    float4 v = make_float4(acc[r][0], acc[r][1], acc[r][2], acc[r][3]);
    *(float4*)&Cm[(size_t)(r0 + rg*4 + r)*D_ + cg*4] = v;
  }
  // alpha epilogue: my 4 cols lie in head hd, cols-within-head cw..cw+3
  int hd = cg >> 3;
  int cw = (cg & 7) * 4;
  float4 u = *(const float4*)&a_s[hd*C_ + cw];
  float4 w = *(const float4*)&a_d[hd*C_ + cw];
  #pragma unroll
  for (int r = 0; r < 4; ++r){
    float s1 = acc[r][0]*u.x + acc[r][1]*u.y + acc[r][2]*u.z + acc[r][3]*u.w;
    float s2 = acc[r][0]*w.x + acc[r][1]*w.y + acc[r][2]*w.z + acc[r][3]*w.w;
    s1 += __shfl_xor(s1, 1); s1 += __shfl_xor(s1, 2); s1 += __shfl_xor(s1, 4);
    s2 += __shfl_xor(s2, 1); s2 += __shfl_xor(s2, 2); s2 += __shfl_xor(s2, 4);
    if ((cg & 7) == 0){
      int row = r0 + rg*4 + r;
      asr[row*4 + hd] = s1;
      adt[row*4 + hd] = s2;
    }
  }
}

// ---------------- CSR build ----------------
__global__ __launch_bounds__(256) void k_count(const int* __restrict__ dst, int* __restrict__ cnt){
  int e = blockIdx.x*256 + threadIdx.x;
  if (e < E_) atomicAdd(&cnt[dst[e]], 1);
}

__global__ __launch_bounds__(256) void k_scan_sums(const int* __restrict__ cnt, int* __restrict__ bsum, int n){
  __shared__ int sd[256];
  int base = blockIdx.x*1024 + threadIdx.x*4;
  int s = 0;
  #pragma unroll
  for (int j = 0; j < 4; ++j){ int i = base + j; if (i < n) s += cnt[i]; }
  sd[threadIdx.x] = s; __syncthreads();
  for (int o = 128; o; o >>= 1){
    if (threadIdx.x < o) sd[threadIdx.x] += sd[threadIdx.x + o];
    __syncthreads();
  }
  if (threadIdx.x == 0) bsum[blockIdx.x] = sd[0];
}

__global__ void k_scan_top(int* bsum, int nblk, int* off){
  if (threadIdx.x == 0 && blockIdx.x == 0){
    int run = 0;
    for (int b = 0; b < nblk; ++b){ int t = bsum[b]; bsum[b] = run; run += t; }
    off[N_] = run;   // == E_
  }
}

__global__ __launch_bounds__(256) void k_scan_apply(const int* __restrict__ cnt,
    const int* __restrict__ bsum, int* __restrict__ off, int n){
  __shared__ int sT[256];
  int base = blockIdx.x*1024 + threadIdx.x*4;
  int v[4]; int t = 0;
  #pragma unroll
  for (int j = 0; j < 4; ++j){ int i = base + j; v[j] = (i < n) ? cnt[i] : 0; t += v[j]; }
  sT[threadIdx.x] = t; __syncthreads();
  for (int o = 1; o < 256; o <<= 1){
    int xv = (threadIdx.x >= o) ? sT[threadIdx.x - o] : 0;
    __syncthreads();
    sT[threadIdx.x] += xv;
    __syncthreads();
  }
  int excl = sT[threadIdx.x] - t;
  int b0v = bsum[blockIdx.x];
  int pre = 0;
  #pragma unroll
  for (int j = 0; j < 4; ++j){ int i = base + j; if (i < n) off[i] = b0v + excl + pre; pre += v[j]; }
}

__global__ __launch_bounds__(256) void k_fill(const int* __restrict__ src, const int* __restrict__ dst,
    const int* __restrict__ off, int* __restrict__ cnt2, int* __restrict__ csr){
  int e = blockIdx.x*256 + threadIdx.x;
  if (e < E_){
    int d = dst[e];
    int pos = off[d] + atomicAdd(&cnt2[d], 1);
    csr[pos] = src[e];
  }
}

// ---------------- fused GAT: one WAVE per node, online softmax ----------------
__global__ __launch_bounds__(256) void k_gat(const float* __restrict__ hW,
    const float* __restrict__ asr, const float* __restrict__ adt,
    const int* __restrict__ off, const int* __restrict__ csr,
    const float* __restrict__ bg, const float* __restrict__ lng, const float* __restrict__ lnb,
    float* __restrict__ h){
  int i = (blockIdx.x * 256 + threadIdx.x) >> 6;   // node = global wave id
  int l = threadIdx.x & 63;
  int beg = off[i], end = off[i + 1];
  int hh = l & 3;

  float adv = adt[i*4 + hh];
  float sself = lrelu(asr[i*4 + hh] + adv);

  // ---- pass 1: online softmax stats (m = running max, z = rebased sum) ----
  float m = sself;
  float z = ((l >> 2) == 0) ? 1.f : 0.f;   // self term carried by one lane per head
  for (int cb = beg; cb < end; cb += 16){
    int e = cb + (l >> 2);
    if (e < end){
      int s = csr[e];
      float v = lrelu(asr[s*4 + hh] + adv);
      if (v > m){ z *= __expf(m - v); m = v; }
      z += __expf(v - m);
    }
  }
  #pragma unroll
  for (int o = 4; o <= 32; o <<= 1){
    float mo = __shfl_xor(m, o);
    float zo = __shfl_xor(z, o);
    float M = fmaxf(m, mo);
    z = z * __expf(m - M) + zo * __expf(mo - M);
    m = M;
  }
  float invz = 1.f / (z + 1e-16f);
  float wsl = __expf(sself - m) * invz;

  // heads owned by my two channels
  int h0 = l >> 5, h1 = 2 + h0;
  float ws0 = __shfl(wsl, h0), ws1 = __shfl(wsl, h1);

  // ---- pass 2: weighted aggregation ----
  size_t ibase = (size_t)i * D_;
  float acc0 = ws0 * hW[ibase + l];
  float acc1 = ws1 * hW[ibase + 64 + l];
  for (int cb = beg; cb < end; cb += 16){
    int e = cb + (l >> 2);
    float al = 0.f; int s = 0;
    if (e < end){
      s = csr[e];
      al = __expf(lrelu(asr[s*4 + hh] + adv) - m) * invz;
    }
    int cn = min(16, end - cb);
    for (int j = 0; j < cn; ++j){
      int   sj = __shfl(s,  j*4);
      float a0 = __shfl(al, j*4 + h0);
      float a1 = __shfl(al, j*4 + h1);
      size_t b = (size_t)sj * D_;
      acc0 += a0 * hW[b + l];
      acc1 += a1 * hW[b + 64 + l];
    }
  }

  // ---- bias + LayerNorm + ReLU + residual ----
  float v0 = acc0 + bg[l], v1 = acc1 + bg[l + 64];
  float sm = v0 + v1;
  #pragma unroll
  for (int o = 1; o < 64; o <<= 1) sm += __shfl_xor(sm, o);
  float mu = sm * (1.f/128.f);
  float d0 = v0 - mu, d1 = v1 - mu;
  float sv = d0*d0 + d1*d1;
  #pragma unroll
  for (int o = 1; o < 64; o <<= 1) sv += __shfl_xor(sv, o);
  float r = rsqrtf(sv * (1.f/128.f) + 1e-5f);
  float y0 = d0 * r * lng[l]      + lnb[l];
  float y1 = d1 * r * lng[l + 64] + lnb[l + 64];
  h[ibase + l]      += fmaxf(y0, 0.f);
  h[ibase + 64 + l] += fmaxf(y1, 0.f);
}

// ---------------- pooling ----------------
__global__ __launch_bounds__(256) void k_starts(const int* __restrict__ batch, int* __restrict__ gst){
  int i = blockIdx.x*256 + threadIdx.x;
  if (i >= N_) return;
  int b = batch[i];
  if (i == 0){
    for (int g = 0; g <= b; ++g) gst[g] = 0;
  } else {
    int pb = batch[i - 1];
    for (int g = pb + 1; g <= b; ++g) gst[g] = i;
  }
  if (i == N_ - 1){
    for (int g = b + 1; g <= G_; ++g) gst[g] = N_;
  }
}

// chunked: 128 rows per block, flush partial sums at graph boundaries
__global__ __launch_bounds__(128) void k_pool(const float* __restrict__ h,
    const int* __restrict__ batch, float* __restrict__ pooled){
  int t = threadIdx.x;
  int r0 = blockIdx.x * 128;
  int rend = min(r0 + 128, N_);
  float acc = 0.f;
  int pg = batch[r0];
  for (int r = r0; r < rend; ++r){
    int g = batch[r];
    if (g != pg){ atomicAdd(&pooled[pg*D_ + t], acc); acc = 0.f; pg = g; }
    acc += h[(size_t)r*D_ + t];
  }
  atomicAdd(&pooled[pg*D_ + t], acc);
}

// ---------------- output head: relu(mean@W1+b1)@W2+b2 ----------------
__global__ __launch_bounds__(128) void k_out(const float* __restrict__ pooled,
    const int* __restrict__ gst,
    const float* __restrict__ W1, const float* __restrict__ b1,
    const float* __restrict__ W2, const float* __restrict__ b2, float* __restrict__ out){
  __shared__ float sp[128], st[128];
  int g = blockIdx.x, t = threadIdx.x;
  float cntg = (float)(gst[g + 1] - gst[g]);
  sp[t] = pooled[g*D_ + t] / fmaxf(cntg, 1.0f);
  __syncthreads();
  float a = b1[t];
  for (int k = 0; k < D_; ++k) a += sp[k] * W1[k*D_ + t];
  st[t] = fmaxf(a, 0.f);
  __syncthreads();
  float o = b2[t];
  for (int k = 0; k < D_; ++k) o += st[k] * W2[k*D_ + t];
  out[g*D_ + t] = o;
}

extern "C" void kernel_launch(void* const* d_in, const int* in_sizes, int n_in,
                              void* d_out, int out_size, void* d_ws, size_t ws_size,
                              hipStream_t stream){
  const float* x   = (const float*)d_in[0];
  const int*   ei  = (const int*)d_in[1];
  const int*   bat = (const int*)d_in[2];
  const float* W0  = (const float*)d_in[3];
  const float* b0  = (const float*)d_in[4];
  const float* Wg  = (const float*)d_in[5];
  const float* a_s = (const float*)d_in[6];
  const float* a_d = (const float*)d_in[7];
  const float* bg  = (const float*)d_in[8];
  const float* lng = (const float*)d_in[9];
  const float* lnb = (const float*)d_in[10];
  const float* W1  = (const float*)d_in[11];
  const float* b1  = (const float*)d_in[12];
  const float* W2  = (const float*)d_in[13];
  const float* b2  = (const float*)d_in[14];
  const int* src = ei;
  const int* dst = ei + E_;

  char* p = (char*)d_ws;
  auto alloc = [&](size_t b){ void* r = (void*)p; p += (b + 255) & ~(size_t)255; return r; };
  float* h    = (float*)alloc((size_t)N_*D_*4);
  float* hW   = (float*)alloc((size_t)N_*D_*4);
  float* asr  = (float*)alloc((size_t)N_*H_*4);
  float* adt  = (float*)alloc((size_t)N_*H_*4);
  int*   cnt  = (int*)alloc((size_t)N_*4);
  int*   cnt2 = (int*)alloc((size_t)N_*4);
  int*   off  = (int*)alloc((size_t)(N_ + 1)*4);
  int*   bsum = (int*)alloc(1024);
  int*   csr  = (int*)alloc((size_t)E_*4);
  int*   gst  = (int*)alloc((size_t)(G_ + 1)*4);
  float* pooled = (float*)alloc((size_t)G_*D_*4);

  hipError_t err;
  err = hipMemsetAsync(cnt,  0, (size_t)N_*4, stream); (void)err;
  err = hipMemsetAsync(cnt2, 0, (size_t)N_*4, stream); (void)err;
  err = hipMemsetAsync(pooled, 0, (size_t)G_*D_*4, stream); (void)err;

  k_embed<<<N_, 128, 0, stream>>>(x, W0, b0, h);

  int nblk = (N_ + 1023) / 1024;
  k_count<<<(E_ + 255)/256, 256, 0, stream>>>(dst, cnt);
  k_scan_sums<<<nblk, 256, 0, stream>>>(cnt, bsum, N_);
  k_scan_top<<<1, 64, 0, stream>>>(bsum, nblk, off);
  k_scan_apply<<<nblk, 256, 0, stream>>>(cnt, bsum, off, N_);
  k_fill<<<(E_ + 255)/256, 256, 0, stream>>>(src, dst, off, cnt2, csr);

  for (int l = 0; l < L_; ++l){
    k_gemm<<<N_/GR, 256, 0, stream>>>(h, Wg + (size_t)l*D_*D_,
                                      a_s + l*H_*C_, a_d + l*H_*C_, hW, asr, adt);
    k_gat<<<N_/4, 256, 0, stream>>>(hW, asr, adt, off, csr, bg + l*D_, lng + l*D_, lnb + l*D_, h);
  }

  k_starts<<<(N_ + 255)/256, 256, 0, stream>>>(bat, gst);
  k_pool<<<(N_ + 127)/128, 128, 0, stream>>>(h, bat, pooled);
  k_out<<<G_, 128, 0, stream>>>(pooled, gst, W1, b1, W2, b2, (float*)d_out);
}